// Round 2
// baseline (1336.268 us; speedup 1.0000x reference)
//
#include <hip/hip_runtime.h>
#include <hip/hip_bf16.h>

#define LOG2E 1.4426950408889634f

using f32x4  = __attribute__((ext_vector_type(4))) float;
using bf16x8 = __attribute__((ext_vector_type(8))) short;
using bf16x4 = __attribute__((ext_vector_type(4))) short;

__device__ __forceinline__ short f2bs(float f) {
    union { __hip_bfloat16 h; short s; } u;
    u.h = __float2bfloat16(f);
    return u.s;
}

__device__ __forceinline__ bf16x4 cvt4(f32x4 a) {
    bf16x4 r;
    r[0] = f2bs(a.x); r[1] = f2bs(a.y); r[2] = f2bs(a.z); r[3] = f2bs(a.w);
    return r;
}

__device__ __forceinline__ bf16x8 cvt8(f32x4 a, f32x4 b) {
    bf16x8 r;
    r[0] = f2bs(a.x); r[1] = f2bs(a.y); r[2] = f2bs(a.z); r[3] = f2bs(a.w);
    r[4] = f2bs(b.x); r[5] = f2bs(b.y); r[6] = f2bs(b.z); r[7] = f2bs(b.w);
    return r;
}

// B=8, S=2048, E=1024. qkv row stride = 3072 floats.
// Block: 512 thr = 8 waves. BQ=32 q-rows per block, BK=256 k per iteration.
// Wave w: QK^T cols w*32..w*32+31; PV out cols w*128..w*128+127.
__global__ __launch_bounds__(512, 2)
void sdpa_flash_kernel(const float* __restrict__ qkv, float* __restrict__ out) {
    // LDS: 66048 + 16896 + 40960 + 1024 + 1024 = 125952 B
    __shared__ short qs[32][1032];      // Q tile bf16, pad 8 (row stride 2064B, 16B-aligned)
    __shared__ short ps[32][264];       // P tile bf16, pad 8 (row stride 528B, 16B-aligned)
    __shared__ short vt[8][64 * 40];    // per-wave V^T half-tile: [64 e][40 shorts] (k-contiguous, pad to 40)
    __shared__ float redm[32][8];       // cross-wave row max
    __shared__ float reds[32][8];       // cross-wave row sum

    const int tid = threadIdx.x;
    const int w   = tid >> 6;
    const int l   = tid & 63;
    const int g   = l >> 4;     // 16-lane group 0..3
    const int c16 = l & 15;
    const int b   = blockIdx.x & 7;   // batch -> XCD
    const int qb  = blockIdx.x >> 3;

    const float* __restrict__ base = qkv + (size_t)b * (2048u * 3072u);
    const float* kp = base + 1024;
    const float* vp = base + 2048;
    float* op = out + (size_t)b * (2048u * 1024u) + (size_t)(qb * 32) * 1024u;

    // ---- stage Q tile (scaled by 1/sqrt(1024)=1/32) as bf16 ----
    #pragma unroll
    for (int i = 0; i < 16; ++i) {
        int fid = i * 512 + tid;        // 0..8191 float4s
        int row = fid >> 8;             // 256 f4 per row
        int c4  = fid & 255;
        f32x4 v = *(const f32x4*)(base + (size_t)(qb * 32 + row) * 3072 + c4 * 4);
        v *= 0.03125f;
        *(bf16x4*)&qs[row][c4 * 4] = cvt4(v);
    }
    __syncthreads();

    f32x4 o[2][8];
    float m_run[2][4], l_run[2][4];
    #pragma unroll
    for (int rt = 0; rt < 2; ++rt)
        #pragma unroll
        for (int j = 0; j < 4; ++j) { m_run[rt][j] = -__builtin_inff(); l_run[rt][j] = 0.f; }
    #pragma unroll
    for (int rt = 0; rt < 2; ++rt)
        #pragma unroll
        for (int c = 0; c < 8; ++c) o[rt][c] = {0.f, 0.f, 0.f, 0.f};

    #pragma unroll 1
    for (int kb = 0; kb < 8; ++kb) {
        // ================= QK^T : S[0:32][kb*256 + w*32 .. +31] =================
        f32x4 sfr[2][2];
        #pragma unroll
        for (int rt = 0; rt < 2; ++rt)
            #pragma unroll
            for (int ct = 0; ct < 2; ++ct) sfr[rt][ct] = {0.f, 0.f, 0.f, 0.f};

        const float* krow0 = kp + (size_t)(kb * 256 + w * 32 + c16) * 3072 + g * 8;

        f32x4 kr[2][2];
        kr[0][0] = *(const f32x4*)(krow0);
        kr[0][1] = *(const f32x4*)(krow0 + 4);
        kr[1][0] = *(const f32x4*)(krow0 + 16 * 3072);
        kr[1][1] = *(const f32x4*)(krow0 + 16 * 3072 + 4);

        #pragma unroll
        for (int es = 0; es < 32; ++es) {
            f32x4 kn[2][2];
            int e2 = (es + 1) * 32;   // es==31 harmlessly reads into V region (in-bounds, discarded)
            kn[0][0] = *(const f32x4*)(krow0 + e2);
            kn[0][1] = *(const f32x4*)(krow0 + e2 + 4);
            kn[1][0] = *(const f32x4*)(krow0 + 16 * 3072 + e2);
            kn[1][1] = *(const f32x4*)(krow0 + 16 * 3072 + e2 + 4);

            bf16x8 aq0 = *(const bf16x8*)&qs[c16][es * 32 + g * 8];
            bf16x8 aq1 = *(const bf16x8*)&qs[16 + c16][es * 32 + g * 8];
            bf16x8 bk0 = cvt8(kr[0][0], kr[0][1]);
            bf16x8 bk1 = cvt8(kr[1][0], kr[1][1]);

            sfr[0][0] = __builtin_amdgcn_mfma_f32_16x16x32_bf16(aq0, bk0, sfr[0][0], 0, 0, 0);
            sfr[0][1] = __builtin_amdgcn_mfma_f32_16x16x32_bf16(aq0, bk1, sfr[0][1], 0, 0, 0);
            sfr[1][0] = __builtin_amdgcn_mfma_f32_16x16x32_bf16(aq1, bk0, sfr[1][0], 0, 0, 0);
            sfr[1][1] = __builtin_amdgcn_mfma_f32_16x16x32_bf16(aq1, bk1, sfr[1][1], 0, 0, 0);

            kr[0][0] = kn[0][0]; kr[0][1] = kn[0][1];
            kr[1][0] = kn[1][0]; kr[1][1] = kn[1][1];
        }

        // ================= online softmax =================
        // C/D layout (HW-verified): row = g*4 + j (+rt*16), col = c16 (+ct*16 + w*32)
        #pragma unroll
        for (int rt = 0; rt < 2; ++rt)
            #pragma unroll
            for (int j = 0; j < 4; ++j) {
                float v = fmaxf(sfr[rt][0][j], sfr[rt][1][j]);
                v = fmaxf(v, __shfl_xor(v, 1));
                v = fmaxf(v, __shfl_xor(v, 2));
                v = fmaxf(v, __shfl_xor(v, 4));
                v = fmaxf(v, __shfl_xor(v, 8));
                if (c16 == 0) redm[rt * 16 + g * 4 + j][w] = v;
            }
        __syncthreads();   // bar A: redm ready

        float mn[2][4], fct[2][4];
        #pragma unroll
        for (int rt = 0; rt < 2; ++rt)
            #pragma unroll
            for (int j = 0; j < 4; ++j) {
                int row = rt * 16 + g * 4 + j;
                float v = redm[row][0];
                #pragma unroll
                for (int w2 = 1; w2 < 8; ++w2) v = fmaxf(v, redm[row][w2]);
                float mold = m_run[rt][j];
                float m2 = fmaxf(mold, v);
                mn[rt][j]  = m2;
                fct[rt][j] = exp2f((mold - m2) * LOG2E);
                m_run[rt][j] = m2;
            }

        float sl[2][4] = {{0.f,0.f,0.f,0.f},{0.f,0.f,0.f,0.f}};
        #pragma unroll
        for (int rt = 0; rt < 2; ++rt)
            #pragma unroll
            for (int ct = 0; ct < 2; ++ct)
                #pragma unroll
                for (int j = 0; j < 4; ++j) {
                    float p = exp2f((sfr[rt][ct][j] - mn[rt][j]) * LOG2E);
                    ps[rt * 16 + g * 4 + j][w * 32 + ct * 16 + c16] = f2bs(p);
                    sl[rt][j] += p;
                }
        #pragma unroll
        for (int rt = 0; rt < 2; ++rt)
            #pragma unroll
            for (int j = 0; j < 4; ++j) {
                float v = sl[rt][j];
                v += __shfl_xor(v, 1);
                v += __shfl_xor(v, 2);
                v += __shfl_xor(v, 4);
                v += __shfl_xor(v, 8);
                if (c16 == 0) reds[rt * 16 + g * 4 + j][w] = v;
            }
        __syncthreads();   // bar B: ps + reds ready

        #pragma unroll
        for (int rt = 0; rt < 2; ++rt)
            #pragma unroll
            for (int j = 0; j < 4; ++j) {
                int row = rt * 16 + g * 4 + j;
                float v = 0.f;
                #pragma unroll
                for (int w2 = 0; w2 < 8; ++w2) v += reds[row][w2];
                l_run[rt][j] = l_run[rt][j] * fct[rt][j] + v;
                #pragma unroll
                for (int c = 0; c < 8; ++c) o[rt][c][j] *= fct[rt][j];
            }

        // ================= PV : O[0:32][w*128 .. +127] += P @ V =================
        // vt layout: element (e, k) at short index e*40 + k (k = 0..31, contiguous).
        // Both P-frag and V-frag use k-slot map k = g*8+s -> symmetric-map immune.
        const float* vp_kb = vp + (size_t)(kb * 256) * 3072 + w * 128;
        #pragma unroll 1
        for (int ks = 0; ks < 8; ++ks) {
            bf16x8 pa0 = *(const bf16x8*)&ps[c16][ks * 32 + g * 8];
            bf16x8 pa1 = *(const bf16x8*)&ps[16 + c16][ks * 32 + g * 8];

            #pragma unroll
            for (int eh = 0; eh < 2; ++eh) {
                // stage V[ks*32 .. +31][w*128 + eh*64 .. +63] transposed into vt[w]
                const float* vbase = vp_kb + (size_t)(ks * 32) * 3072 + eh * 64;
                #pragma unroll
                for (int i = 0; i < 2; ++i) {
                    int blk = i * 64 + l;           // 0..127 = 8 kq x 16 cb
                    int kq  = blk & 7;              // rows kq*4 .. +3
                    int cb  = (blk >> 3) & 15;      // cols cb*4 .. +3
                    f32x4 r0 = *(const f32x4*)(vbase + (size_t)(kq * 4 + 0) * 3072 + cb * 4);
                    f32x4 r1 = *(const f32x4*)(vbase + (size_t)(kq * 4 + 1) * 3072 + cb * 4);
                    f32x4 r2 = *(const f32x4*)(vbase + (size_t)(kq * 4 + 2) * 3072 + cb * 4);
                    f32x4 r3 = *(const f32x4*)(vbase + (size_t)(kq * 4 + 3) * 3072 + cb * 4);
                    #pragma unroll
                    for (int j = 0; j < 4; ++j) {
                        bf16x4 cw;
                        cw[0] = f2bs(r0[j]); cw[1] = f2bs(r1[j]);
                        cw[2] = f2bs(r2[j]); cw[3] = f2bs(r3[j]);
                        *(bf16x4*)&vt[w][(cb * 4 + j) * 40 + kq * 4] = cw;
                    }
                }
                // per-wave private region + in-wave LDS FIFO ordering: no barrier needed;
                // compiler inserts lgkmcnt before dependent reads below.

                #pragma unroll
                for (int ct2 = 0; ct2 < 4; ++ct2) {
                    bf16x8 bv = *(const bf16x8*)&vt[w][(ct2 * 16 + c16) * 40 + g * 8];
                    o[0][eh * 4 + ct2] = __builtin_amdgcn_mfma_f32_16x16x32_bf16(pa0, bv, o[0][eh * 4 + ct2], 0, 0, 0);
                    o[1][eh * 4 + ct2] = __builtin_amdgcn_mfma_f32_16x16x32_bf16(pa1, bv, o[1][eh * 4 + ct2], 0, 0, 0);
                }
            }
        }
        __syncthreads();   // bar C: done with ps/redm/reds before next kb overwrites
    }

    // ================= epilogue: O / l =================
    #pragma unroll
    for (int rt = 0; rt < 2; ++rt)
        #pragma unroll
        for (int j = 0; j < 4; ++j) {
            float inv = 1.0f / l_run[rt][j];
            int row = rt * 16 + g * 4 + j;
            #pragma unroll
            for (int c = 0; c < 8; ++c)
                op[(size_t)row * 1024 + w * 128 + c * 16 + c16] = o[rt][c][j] * inv;
        }
}

extern "C" void kernel_launch(void* const* d_in, const int* in_sizes, int n_in,
                              void* d_out, int out_size, void* d_ws, size_t ws_size,
                              hipStream_t stream) {
    const float* qkv = (const float*)d_in[0];
    float* out = (float*)d_out;
    sdpa_flash_kernel<<<dim3(512), dim3(512), 0, stream>>>(qkv, out);
}